// Round 3
// baseline (883.860 us; speedup 1.0000x reference)
//
#include <hip/hip_runtime.h>
#include <cstddef>
#include <cstdint>

typedef unsigned short u16;
typedef unsigned int   u32;
typedef __attribute__((ext_vector_type(8))) short          bf16x8;
typedef __attribute__((ext_vector_type(4))) float          f32x4;
typedef __attribute__((ext_vector_type(4))) unsigned short u16x4;

#define S_LEN 2048
#define DM    1024
#define NROWS 4096
#define QSCALE 0.18033688011112042f   /* 0.125 * log2(e) */
#define SOFTC  28.853900817779268f    /* 20 * log2(e)    */

__device__ __forceinline__ u16 f2bf(float x) {
  u32 u = __float_as_uint(x);
  return (u16)((u + 0x7fffu + ((u >> 16) & 1u)) >> 16);
}
__device__ __forceinline__ float bf2f(u16 h) { return __uint_as_float(((u32)h) << 16); }
__device__ __forceinline__ u32 cvtpk(float lo, float hi) {
  u32 r; asm("v_cvt_pk_bf16_f32 %0, %1, %2" : "=v"(r) : "v"(lo), "v"(hi)); return r;
}
__device__ __forceinline__ void gld16(const void* g, void* l) {
  __builtin_amdgcn_global_load_lds((const __attribute__((address_space(1))) void*)g,
                                   (__attribute__((address_space(3))) void*)l, 16, 0, 0);
}
__device__ __forceinline__ int swz4(int r) { return (r & 3) ^ ((r >> 2) & 3); }
#define MFMA16(a,b,c) __builtin_amdgcn_mfma_f32_16x16x32_bf16(a,b,c,0,0,0)

// ---------------- fused fp32 -> (hi,lo) bf16 split for all 7 tensors ---------
struct SplitArgs { const float* s[7]; u16* h[7]; u16* l[7]; int n4[7]; };

__global__ __launch_bounds__(256) void splitk7(SplitArgs a) {
  const int y = blockIdx.y;
  const float* s = a.s[y];
  u16* h = a.h[y]; u16* l = a.l[y];
  const int n4 = a.n4[y];
  const int step = gridDim.x * 256;
  for (int i = blockIdx.x * 256 + threadIdx.x; i < n4; i += step) {
    float4 v = ((const float4*)s)[i];
    u16x4 hh, ll; u16 x;
    x = f2bf(v.x); hh[0] = x; ll[0] = f2bf(v.x - bf2f(x));
    x = f2bf(v.y); hh[1] = x; ll[1] = f2bf(v.y - bf2f(x));
    x = f2bf(v.z); hh[2] = x; ll[2] = f2bf(v.z - bf2f(x));
    x = f2bf(v.w); hh[3] = x; ll[3] = f2bf(v.w - bf2f(x));
    *(u16x4*)&h[(size_t)i * 4] = hh;
    *(u16x4*)&l[(size_t)i * 4] = ll;
  }
}

// ---------------- split-bf16 GEMM: C = A @ W^T + bias, 128x128 tile ---------
// A: [4096][1024] hi/lo, W: [1024][1024] hi/lo row-major (K contiguous).
// EPI 0: split-store [BH,S,64] (+scale). EPI 1: split-store V^T [BH,64,S].
// EPI 2: fp32 row-major [4096][1024].
template<int EPI>
__global__ __launch_bounds__(256) void gemm_split(
    const u16* __restrict__ Ah, const u16* __restrict__ Al,
    const u16* __restrict__ Bh, const u16* __restrict__ Bl,
    const float* __restrict__ bias,
    u16* __restrict__ Oh, u16* __restrict__ Ol, float* __restrict__ Of,
    float scale)
{
  __shared__ __align__(16) u16 lds[2][16384];  // Ahi Alo Bhi Blo, each [128][32]
  const int t = threadIdx.x;
  const int id = blockIdx.x;
  const int bn = (id & 7) * 128;     // N-panel == XCD (L2 reuse of W)
  const int bm = (id >> 3) * 128;
  const int lane = t & 63, w = t >> 6;
  const int u = lane >> 4, c15 = lane & 15;
  const int wr = (w >> 1) * 64, wc = (w & 1) * 64;

  f32x4 acc[4][4];
#pragma unroll
  for (int i = 0; i < 4; ++i)
#pragma unroll
    for (int j = 0; j < 4; ++j) acc[i][j] = (f32x4){0.f, 0.f, 0.f, 0.f};

  auto stage = [&](int buf, int kb) {
    u16* L = lds[buf];
#pragma unroll
    for (int pp = 0; pp < 2; ++pp) {
      const int q = t + pp * 256;           // chunk slot 0..511
      const int row = q >> 2;
      const int ch = (q & 3) ^ swz4(row);   // inverse-swizzled global source
      const int co = kb + 8 * ch;
      gld16(Ah + (size_t)(bm + row) * DM + co, L + q * 8);
      gld16(Al + (size_t)(bm + row) * DM + co, L + 4096 + q * 8);
      gld16(Bh + (size_t)(bn + row) * DM + co, L + 8192 + q * 8);
      gld16(Bl + (size_t)(bn + row) * DM + co, L + 12288 + q * 8);
    }
  };

  stage(0, 0);
  __syncthreads();
  int buf = 0;
  for (int kb = 0; kb < DM; kb += 32) {
    if (kb + 32 < DM) stage(buf ^ 1, kb + 32);
    const u16* L = lds[buf];
    bf16x8 ah[4], al[4];
#pragma unroll
    for (int i = 0; i < 4; ++i) {
      const int r = wr + 16 * i + c15;
      const int off = r * 32 + 8 * (u ^ swz4(r));
      ah[i] = *(const bf16x8*)&L[off];
      al[i] = *(const bf16x8*)&L[4096 + off];
    }
#pragma unroll
    for (int j = 0; j < 4; ++j) {
      const int n = wc + 16 * j + c15;
      const int off = n * 32 + 8 * (u ^ swz4(n));
      bf16x8 bh8 = *(const bf16x8*)&L[8192 + off];
      bf16x8 bl8 = *(const bf16x8*)&L[12288 + off];
#pragma unroll
      for (int i = 0; i < 4; ++i) {
        acc[i][j] = MFMA16(ah[i], bh8, acc[i][j]);
        acc[i][j] = MFMA16(ah[i], bl8, acc[i][j]);
        acc[i][j] = MFMA16(al[i], bh8, acc[i][j]);
      }
    }
    __syncthreads();
    buf ^= 1;
  }

#pragma unroll
  for (int j = 0; j < 4; ++j) {
    const int n = bn + wc + 16 * j + c15;
    const float bv = bias[n];
#pragma unroll
    for (int i = 0; i < 4; ++i) {
      float v[4];
#pragma unroll
      for (int r = 0; r < 4; ++r) v[r] = (acc[i][j][r] + bv) * scale;
      const int m0 = bm + wr + 16 * i + 4 * u;
      if (EPI == 2) {
#pragma unroll
        for (int r = 0; r < 4; ++r) Of[(size_t)(m0 + r) * DM + n] = v[r];
      } else if (EPI == 0) {
#pragma unroll
        for (int r = 0; r < 4; ++r) {
          const int m = m0 + r;
          const int b_ = m >> 11, s_ = m & 2047, h_ = n >> 6, d_ = n & 63;
          const size_t idx = (((size_t)(b_ * 16 + h_)) * S_LEN + s_) * 64 + d_;
          u16 hh = f2bf(v[r]);
          Oh[idx] = hh; Ol[idx] = f2bf(v[r] - bf2f(hh));
        }
      } else {  // EPI 1: V^T [BH][64][S]
        u16x4 hv, lv;
#pragma unroll
        for (int r = 0; r < 4; ++r) {
          u16 hh = f2bf(v[r]); hv[r] = hh; lv[r] = f2bf(v[r] - bf2f(hh));
        }
        const int b_ = m0 >> 11, s_ = m0 & 2047, h_ = n >> 6, d_ = n & 63;
        const size_t idx = (((size_t)(b_ * 16 + h_)) * 64 + d_) * S_LEN + s_;
        *(u16x4*)&Oh[idx] = hv; *(u16x4*)&Ol[idx] = lv;
      }
    }
  }
}

// ---------------- fused causal attention, split-bf16 MFMA --------------------
__global__ __launch_bounds__(256) void attn_mfma(
    const u16* __restrict__ Qh, const u16* __restrict__ Ql,
    const u16* __restrict__ Kh, const u16* __restrict__ Kl,
    const u16* __restrict__ Vh, const u16* __restrict__ Vl,
    float* __restrict__ attnO, u16* __restrict__ Oh, u16* __restrict__ Ol)
{
  __shared__ __align__(16) u16 Kbuf[2][2][4096];
  __shared__ __align__(16) u16 Vbuf[2][4096];
  __shared__ __align__(16) float Pbuf[64][68];   // +4 pad: conflict-free reads

  const int t = threadIdx.x;
  const int id = blockIdx.x;               // XCD-chunked: 4 bh per XCD
  const int bh = (id & 7) * 4 + ((id >> 3) >> 4);
  const int pair = (id >> 3) & 15;
  const int lane = t & 63, w = t >> 6;
  const int u = lane >> 4, c15 = lane & 15;
  const size_t kvbase = (size_t)bh * S_LEN * 64;

  auto stageK = [&](int bb, int tk) {
    const int x = t >> 3, p = t & 7;
    const int co = 8 * (p ^ (x & 7));
    const u16* bH = Kh + kvbase + (size_t)tk * 4096;
    const u16* bL = Kl + kvbase + (size_t)tk * 4096;
    gld16(bH + (size_t)x * 64 + co,        &Kbuf[bb][0][t * 8]);
    gld16(bH + (size_t)(x + 32) * 64 + co, &Kbuf[bb][0][2048 + t * 8]);
    gld16(bL + (size_t)x * 64 + co,        &Kbuf[bb][1][t * 8]);
    gld16(bL + (size_t)(x + 32) * 64 + co, &Kbuf[bb][1][2048 + t * 8]);
  };
  auto stageV = [&](int tk) {
    const int x = t >> 3, p = t & 7;
    const int co = 8 * (p ^ (x & 7));
    const u16* bH = Vh + kvbase + (size_t)tk * 64;
    const u16* bL = Vl + kvbase + (size_t)tk * 64;
    gld16(bH + (size_t)x * S_LEN + co,        &Vbuf[0][t * 8]);
    gld16(bH + (size_t)(x + 32) * S_LEN + co, &Vbuf[0][2048 + t * 8]);
    gld16(bL + (size_t)x * S_LEN + co,        &Vbuf[1][t * 8]);
    gld16(bL + (size_t)(x + 32) * S_LEN + co, &Vbuf[1][2048 + t * 8]);
  };

  // zero-fill strict-upper attn region (256B segments)
  {
    const int rr0 = t >> 4, cq = t & 15;
    const float4 z = make_float4(0.f, 0.f, 0.f, 0.f);
#pragma unroll
    for (int which = 0; which < 2; ++which) {
      const int qb2 = which ? (31 - pair) : pair;
#pragma unroll
      for (int pp = 0; pp < 4; ++pp) {
        const int row = pp * 16 + rr0;
        float4* rowp = (float4*)(attnO + ((size_t)bh * S_LEN + qb2 * 64 + row) * S_LEN);
        for (int c4 = (qb2 + 1) * 16 + cq; c4 < 512; c4 += 16) rowp[c4] = z;
      }
    }
  }

  for (int which = 0; which < 2; ++which) {
    const int qb = which ? (31 - pair) : pair;
    const int q0 = qb * 64;

    const size_t qrow = kvbase + (size_t)(q0 + 16 * w + c15) * 64;
    bf16x8 qfh[2], qfl[2];
    qfh[0] = *(const bf16x8*)&Qh[qrow + 8 * u];
    qfh[1] = *(const bf16x8*)&Qh[qrow + 32 + 8 * u];
    qfl[0] = *(const bf16x8*)&Ql[qrow + 8 * u];
    qfl[1] = *(const bf16x8*)&Ql[qrow + 32 + 8 * u];

    float lsum[4] = {0.f, 0.f, 0.f, 0.f};

    // ---------- pass 1: denominators (per-lane partials, deferred reduce) ----
    int b = 0;
    stageK(0, 0);
    __syncthreads();
    for (int tk = 0; tk <= qb; ++tk) {
      if (tk < qb) stageK(b ^ 1, tk + 1);
      f32x4 sacc[4];
#pragma unroll
      for (int j = 0; j < 4; ++j) sacc[j] = (f32x4){0.f, 0.f, 0.f, 0.f};
      __builtin_amdgcn_s_setprio(1);
#pragma unroll
      for (int j = 0; j < 4; ++j) {
        const int srow = 16 * j + c15;
#pragma unroll
        for (int h = 0; h < 2; ++h) {
          const int off = srow * 64 + 8 * ((4 * h + u) ^ (srow & 7));
          bf16x8 kbh = *(const bf16x8*)&Kbuf[b][0][off];
          bf16x8 kbl = *(const bf16x8*)&Kbuf[b][1][off];
          sacc[j] = MFMA16(qfh[h], kbh, sacc[j]);
          sacc[j] = MFMA16(qfh[h], kbl, sacc[j]);
          sacc[j] = MFMA16(qfl[h], kbh, sacc[j]);
        }
      }
      __builtin_amdgcn_s_setprio(0);
      const bool dg = (tk == qb);
#pragma unroll
      for (int r = 0; r < 4; ++r) {
        const int qg = 16 * w + 4 * u + r;
#pragma unroll
        for (int j = 0; j < 4; ++j) {
          const int sg = tk * 64 + 16 * j + c15;
          const bool keep = (!dg) || (sg <= q0 + qg);
          lsum[r] += keep ? exp2f(sacc[j][r] - SOFTC) : 0.f;
        }
      }
      __syncthreads();
      b ^= 1;
    }

    float linv[4];
#pragma unroll
    for (int r = 0; r < 4; ++r) {
      float s = lsum[r];
      s += __shfl_xor(s, 1); s += __shfl_xor(s, 2);
      s += __shfl_xor(s, 4); s += __shfl_xor(s, 8);
      linv[r] = 1.0f / s;
    }

    // ---------- pass 2: normalize, write attn, PV ----------
    b = 0;
    stageK(0, 0);
    __syncthreads();
    f32x4 oacc[4];
#pragma unroll
    for (int j = 0; j < 4; ++j) oacc[j] = (f32x4){0.f, 0.f, 0.f, 0.f};

    for (int tk = 0; tk <= qb; ++tk) {
      stageV(tk);
      if (tk < qb) stageK(b ^ 1, tk + 1);
      f32x4 sacc[4];
#pragma unroll
      for (int j = 0; j < 4; ++j) sacc[j] = (f32x4){0.f, 0.f, 0.f, 0.f};
      __builtin_amdgcn_s_setprio(1);
#pragma unroll
      for (int j = 0; j < 4; ++j) {
        const int srow = 16 * j + c15;
#pragma unroll
        for (int h = 0; h < 2; ++h) {
          const int off = srow * 64 + 8 * ((4 * h + u) ^ (srow & 7));
          bf16x8 kbh = *(const bf16x8*)&Kbuf[b][0][off];
          bf16x8 kbl = *(const bf16x8*)&Kbuf[b][1][off];
          sacc[j] = MFMA16(qfh[h], kbh, sacc[j]);
          sacc[j] = MFMA16(qfh[h], kbl, sacc[j]);
          sacc[j] = MFMA16(qfl[h], kbh, sacc[j]);
        }
      }
      __builtin_amdgcn_s_setprio(0);
      const bool dg = (tk == qb);
#pragma unroll
      for (int r = 0; r < 4; ++r) {
        const int qg = 16 * w + 4 * u + r;
        const float iv = linv[r];
#pragma unroll
        for (int j = 0; j < 4; ++j) {
          const int sl = 16 * j + c15;
          const int sg = tk * 64 + sl;
          const bool keep = (!dg) || (sg <= q0 + qg);
          Pbuf[qg][sl] = keep ? exp2f(sacc[j][r] - SOFTC) * iv : 0.f;
        }
      }
      __syncthreads();   // Pbuf ready; V tile arrived (vmcnt drained at barrier)

      // PV: fragments built reader-side via v_cvt_pk_bf16_f32
      __builtin_amdgcn_s_setprio(1);
      {
        const int qloc = 16 * w + c15;
#pragma unroll
        for (int h = 0; h < 2; ++h) {
          f32x4 pa = *(const f32x4*)&Pbuf[qloc][32 * h + 8 * u];
          f32x4 pb = *(const f32x4*)&Pbuf[qloc][32 * h + 8 * u + 4];
          union { bf16x8 v; u32 x[4]; } H, L;
          H.x[0] = cvtpk(pa[0], pa[1]);
          H.x[1] = cvtpk(pa[2], pa[3]);
          H.x[2] = cvtpk(pb[0], pb[1]);
          H.x[3] = cvtpk(pb[2], pb[3]);
          float l0, l1;
          l0 = pa[0] - __uint_as_float(H.x[0] << 16);
          l1 = pa[1] - __uint_as_float(H.x[0] & 0xffff0000u);
          L.x[0] = cvtpk(l0, l1);
          l0 = pa[2] - __uint_as_float(H.x[1] << 16);
          l1 = pa[3] - __uint_as_float(H.x[1] & 0xffff0000u);
          L.x[1] = cvtpk(l0, l1);
          l0 = pb[0] - __uint_as_float(H.x[2] << 16);
          l1 = pb[1] - __uint_as_float(H.x[2] & 0xffff0000u);
          L.x[2] = cvtpk(l0, l1);
          l0 = pb[2] - __uint_as_float(H.x[3] << 16);
          l1 = pb[3] - __uint_as_float(H.x[3] & 0xffff0000u);
          L.x[3] = cvtpk(l0, l1);
#pragma unroll
          for (int j = 0; j < 4; ++j) {
            const int dr = 16 * j + c15;
            const int off = dr * 64 + 8 * ((4 * h + u) ^ (dr & 7));
            bf16x8 vH = *(const bf16x8*)&Vbuf[0][off];
            bf16x8 vL = *(const bf16x8*)&Vbuf[1][off];
            oacc[j] = MFMA16(H.v, vH, oacc[j]);
            oacc[j] = MFMA16(H.v, vL, oacc[j]);
            oacc[j] = MFMA16(L.v, vH, oacc[j]);
          }
        }
      }
      __builtin_amdgcn_s_setprio(0);

      // attn global store from Pbuf: 256B segments, exact fp32 pn
      {
        const int rr0 = t >> 4;
        const int cc = (t & 15) * 4;
        float* abase = attnO + ((size_t)bh * S_LEN + q0) * S_LEN + (size_t)tk * 64;
#pragma unroll
        for (int pp = 0; pp < 4; ++pp) {
          const int row = pp * 16 + rr0;
          f32x4 pv = *(const f32x4*)&Pbuf[row][cc];
          *(float4*)(abase + (size_t)row * S_LEN + cc) =
              make_float4(pv[0], pv[1], pv[2], pv[3]);
        }
      }
      __syncthreads();   // Pbuf/Vbuf reads done -> next iter may overwrite
      b ^= 1;
    }

    // write O (split bf16) to [B,S,D] row-major
    const int bb = bh >> 4, hh = bh & 15;
#pragma unroll
    for (int j = 0; j < 4; ++j) {
      const int d = 16 * j + c15;
#pragma unroll
      for (int r = 0; r < 4; ++r) {
        const int qg = q0 + 16 * w + 4 * u + r;
        const float v = oacc[j][r];
        const u16 hi = f2bf(v);
        const size_t idx = ((size_t)bb * S_LEN + qg) * DM + hh * 64 + d;
        Oh[idx] = hi; Ol[idx] = f2bf(v - bf2f(hi));
      }
    }
  }
}

// ---------------- launch -----------------------------------------------------
extern "C" void kernel_launch(void* const* d_in, const int* in_sizes, int n_in,
                              void* d_out, int out_size, void* d_ws, size_t ws_size,
                              hipStream_t stream) {
  const float* Q  = (const float*)d_in[0];
  const float* K  = (const float*)d_in[1];
  const float* V  = (const float*)d_in[2];
  const float* Wq = (const float*)d_in[4];
  const float* bq = (const float*)d_in[5];
  const float* Wk = (const float*)d_in[6];
  const float* bk = (const float*)d_in[7];
  const float* Wv = (const float*)d_in[8];
  const float* bv = (const float*)d_in[9];
  const float* Wo = (const float*)d_in[10];
  const float* bo = (const float*)d_in[11];

  float* out  = (float*)d_out;                  // [B,S,D]
  float* attn = out + (size_t)NROWS * DM;       // [B,H,S,S]

  u16* base = (u16*)d_ws;
  const size_t XN = (size_t)NROWS * DM;   // 4,194,304
  const size_t WN = (size_t)DM * DM;      // 1,048,576
  u16* xqh = base;       u16* xql = xqh + XN;
  u16* xkh = xql + XN;   u16* xkl = xkh + XN;
  u16* xvh = xkl + XN;   u16* xvl = xvh + XN;
  u16* wqh = xvl + XN;   u16* wql = wqh + WN;
  u16* wkh = wql + WN;   u16* wkl = wkh + WN;
  u16* wvh = wkl + WN;   u16* wvl = wvh + WN;
  u16* woh = wvl + WN;   u16* wol = woh + WN;
  u16* Qph = wol + WN;   u16* Qpl = Qph + XN;
  u16* Kph = Qpl + XN;   u16* Kpl = Kph + XN;
  u16* Vth = Kpl + XN;   u16* Vtl = Vth + XN;
  u16* Oh2 = Vtl + XN;   u16* Ol2 = Oh2 + XN;

  SplitArgs sa;
  sa.s[0] = Q;  sa.h[0] = xqh; sa.l[0] = xql; sa.n4[0] = (int)(XN / 4);
  sa.s[1] = K;  sa.h[1] = xkh; sa.l[1] = xkl; sa.n4[1] = (int)(XN / 4);
  sa.s[2] = V;  sa.h[2] = xvh; sa.l[2] = xvl; sa.n4[2] = (int)(XN / 4);
  sa.s[3] = Wq; sa.h[3] = wqh; sa.l[3] = wql; sa.n4[3] = (int)(WN / 4);
  sa.s[4] = Wk; sa.h[4] = wkh; sa.l[4] = wkl; sa.n4[4] = (int)(WN / 4);
  sa.s[5] = Wv; sa.h[5] = wvh; sa.l[5] = wvl; sa.n4[5] = (int)(WN / 4);
  sa.s[6] = Wo; sa.h[6] = woh; sa.l[6] = wol; sa.n4[6] = (int)(WN / 4);

  splitk7<<<dim3(1024, 7), 256, 0, stream>>>(sa);

  gemm_split<0><<<256, 256, 0, stream>>>(xqh, xql, wqh, wql, bq, Qph, Qpl, nullptr, QSCALE);
  gemm_split<0><<<256, 256, 0, stream>>>(xkh, xkl, wkh, wkl, bk, Kph, Kpl, nullptr, 1.0f);
  gemm_split<1><<<256, 256, 0, stream>>>(xvh, xvl, wvh, wvl, bv, Vth, Vtl, nullptr, 1.0f);

  attn_mfma<<<512, 256, 0, stream>>>(Qph, Qpl, Kph, Kpl, Vth, Vtl, attn, Oh2, Ol2);

  gemm_split<2><<<256, 256, 0, stream>>>(Oh2, Ol2, woh, wol, bo, nullptr, nullptr, out, 1.0f);
}